// Round 1
// baseline (4445.793 us; speedup 1.0000x reference)
//
#include <hip/hip_runtime.h>
#include <hip/hip_bf16.h>

#define NN 200000
#define EE 600000
#define ND 32
#define EMB 128
#define NI_C 120000
#define NEGS 0.1f
#define LNEPS 1e-5f

__device__ __forceinline__ float leakyf(float x) { return x >= 0.0f ? x : NEGS * x; }
__device__ __forceinline__ void fma4(float4& a, float s, const float4& w) {
    a.x = fmaf(s, w.x, a.x); a.y = fmaf(s, w.y, a.y);
    a.z = fmaf(s, w.z, a.z); a.w = fmaf(s, w.w, a.w);
}
__device__ __forceinline__ float bfu2f(unsigned int u) { return __uint_as_float(u << 16); }

// ---------------- degree histogram + normalization ----------------
__global__ __launch_bounds__(256) void k_hist(const int* __restrict__ ei_nn,
                                              const int* __restrict__ ei_net,
                                              int* __restrict__ cnt_nn,
                                              int* __restrict__ cnt_net) {
    int e = blockIdx.x * 256 + threadIdx.x;
    if (e < EE) {
        atomicAdd(&cnt_nn[ei_nn[e]], 1);   // row of node_net edges
        atomicAdd(&cnt_net[ei_net[e]], 1); // row of net_node edges
    }
}

__global__ __launch_bounds__(256) void k_deg(const int* __restrict__ cnt_nn,
                                             const int* __restrict__ cnt_net,
                                             float* __restrict__ isq_nn, float* __restrict__ idg_nn,
                                             float* __restrict__ isq_net, float* __restrict__ idg_net) {
    int n = blockIdx.x * 256 + threadIdx.x;
    if (n < NN) {
        float d1 = (float)(cnt_nn[n] + 1);
        isq_nn[n] = rsqrtf(d1); idg_nn[n] = 1.0f / d1;
        float d2 = (float)(cnt_net[n] + 1);
        isq_net[n] = rsqrtf(d2); idg_net[n] = 1.0f / d2;
    }
}

// ---------------- encoder: h0 = leaky(leaky(x@W1+b1)@W2+b2) ----------------
// 64 nodes/block, 256 threads. LDS: x tile (8KB fp32) + hidden (32KB bf16) = 40KB.
__global__ __launch_bounds__(256) void k_encoder(const float* __restrict__ x,
                                                 const float* __restrict__ w1, const float* __restrict__ b1,
                                                 const float* __restrict__ w2, const float* __restrict__ b2,
                                                 float* __restrict__ H, float* __restrict__ out) {
    __shared__ float4 xs[512];                         // [64][32] floats
    __shared__ __align__(16) __hip_bfloat16 hs[64 * 256];
    int tid = threadIdx.x;
    int n0 = blockIdx.x * 64;

    const float4* xg = (const float4*)(x + (size_t)n0 * ND);
    for (int p = tid; p < 512; p += 256) xs[p] = xg[p];
    __syncthreads();

    // stage 1: thread j computes hidden[:, j] for 64 nodes
    {
        float w[32];
#pragma unroll
        for (int k = 0; k < 32; k++) w[k] = w1[k * 256 + tid];
        float bj = b1[tid];
        for (int n = 0; n < 64; n++) {
            float acc = bj;
#pragma unroll
            for (int k4 = 0; k4 < 8; k4++) {
                float4 xv = xs[n * 8 + k4];
                acc = fmaf(xv.x, w[4 * k4 + 0], acc);
                acc = fmaf(xv.y, w[4 * k4 + 1], acc);
                acc = fmaf(xv.z, w[4 * k4 + 2], acc);
                acc = fmaf(xv.w, w[4 * k4 + 3], acc);
            }
            hs[n * 256 + tid] = __float2bfloat16(leakyf(acc));
        }
    }
    __syncthreads();

    // stage 2: thread (tx,ty): outs o=4*tx..4*tx+3, nodes ty*8..ty*8+7, K=256
    int tx = tid & 31, ty = tid >> 5;
    float4 bias = ((const float4*)b2)[tx];
    float4 acc[8];
#pragma unroll
    for (int i = 0; i < 8; i++) acc[i] = bias;

    const float4* w2g = (const float4*)w2;
    const unsigned short* hsu = (const unsigned short*)hs;
    for (int k4 = 0; k4 < 64; k4++) {
        float4 w0 = w2g[(4 * k4 + 0) * 32 + tx];
        float4 wv1 = w2g[(4 * k4 + 1) * 32 + tx];
        float4 wv2 = w2g[(4 * k4 + 2) * 32 + tx];
        float4 wv3 = w2g[(4 * k4 + 3) * 32 + tx];
#pragma unroll
        for (int i = 0; i < 8; i++) {
            int n = ty * 8 + i;
            uint2 hv = *(const uint2*)(hsu + n * 256 + 4 * k4);
            float a0 = bfu2f(hv.x & 0xffffu);
            float a1 = bfu2f(hv.x >> 16);
            float a2 = bfu2f(hv.y & 0xffffu);
            float a3 = bfu2f(hv.y >> 16);
            fma4(acc[i], a0, w0); fma4(acc[i], a1, wv1);
            fma4(acc[i], a2, wv2); fma4(acc[i], a3, wv3);
        }
    }
#pragma unroll
    for (int i = 0; i < 8; i++) {
        int n = n0 + ty * 8 + i;
        float4 v;
        v.x = leakyf(acc[i].x); v.y = leakyf(acc[i].y);
        v.z = leakyf(acc[i].z); v.w = leakyf(acc[i].w);
        ((float4*)H)[(size_t)n * 32 + tx] = v;
        if (n < NI_C) ((float4*)out)[(size_t)n * 128 + tx] = v;  // cols 0:128
    }
}

// ---------------- XL = A @ W + b  (A:[N,128], W:[128,128]) ----------------
// 64 nodes/block, 256 threads, A tile in LDS (32KB), W streamed from L2.
__global__ __launch_bounds__(256) void k_matmul(const float* __restrict__ A,
                                                const float* __restrict__ W,
                                                const float* __restrict__ bias,
                                                float* __restrict__ out) {
    __shared__ float4 As[2048];  // [64][128] floats
    int tid = threadIdx.x;
    int n0 = blockIdx.x * 64;
    const float4* Ag = (const float4*)(A + (size_t)n0 * EMB);
    for (int p = tid; p < 2048; p += 256) As[p] = Ag[p];
    __syncthreads();

    int tx = tid & 31, ty = tid >> 5;
    const float4* Wg = (const float4*)W;
    float4 bias4 = ((const float4*)bias)[tx];
    float4 acc[8];
#pragma unroll
    for (int i = 0; i < 8; i++) acc[i] = bias4;

    for (int k4 = 0; k4 < 32; k4++) {
        float4 w0 = Wg[(4 * k4 + 0) * 32 + tx];
        float4 w1 = Wg[(4 * k4 + 1) * 32 + tx];
        float4 w2 = Wg[(4 * k4 + 2) * 32 + tx];
        float4 w3 = Wg[(4 * k4 + 3) * 32 + tx];
#pragma unroll
        for (int i = 0; i < 8; i++) {
            float4 a = As[(ty * 8 + i) * 32 + k4];
            fma4(acc[i], a.x, w0); fma4(acc[i], a.y, w1);
            fma4(acc[i], a.z, w2); fma4(acc[i], a.w, w3);
        }
    }
    float4* og = (float4*)out;
#pragma unroll
    for (int i = 0; i < 8; i++) og[(size_t)(n0 + ty * 8 + i) * 32 + tx] = acc[i];
}

// ---------------- edge scatter: AGG[col] += norm * relu(XL[row]) ----------------
// one wave (64 lanes) per edge, float2 per lane
__global__ __launch_bounds__(256) void k_scatter(const float* __restrict__ XL,
                                                 float* __restrict__ AGG,
                                                 const int* __restrict__ ei,
                                                 const float* __restrict__ isq) {
    int t = blockIdx.x * 256 + threadIdx.x;
    int e = t >> 6;
    int lane = t & 63;
    int r = ei[e];
    int c = ei[EE + e];
    float nrm = isq[r] * isq[c];
    float2 v = ((const float2*)XL)[(size_t)r * 64 + lane];
    float m0 = fmaxf(v.x, 0.0f) * nrm;
    float m1 = fmaxf(v.y, 0.0f) * nrm;
    float* dst = AGG + (size_t)c * 128 + lane * 2;
    unsafeAtomicAdd(dst, m0);
    unsafeAtomicAdd(dst + 1, m1);
}

// ---------------- self term (first GCN of each layer) ----------------
// AGG[n] += relu(XL[n] + root) * inv_deg[n]
__global__ __launch_bounds__(256) void k_self1(float* __restrict__ AGG,
                                               const float* __restrict__ XL,
                                               const float* __restrict__ root,
                                               const float* __restrict__ idg) {
    int t = blockIdx.x * 256 + threadIdx.x;  // float4 index over N*32
    int n = t >> 5;
    int q = t & 31;
    float4 xv = ((const float4*)XL)[t];
    float4 rv = ((const float4*)root)[q];
    float id = idg[n];
    float4 g = ((float4*)AGG)[t];
    g.x += fmaxf(xv.x + rv.x, 0.0f) * id;
    g.y += fmaxf(xv.y + rv.y, 0.0f) * id;
    g.z += fmaxf(xv.z + rv.z, 0.0f) * id;
    g.w += fmaxf(xv.w + rv.w, 0.0f) * id;
    ((float4*)AGG)[t] = g;
}

// ---------------- epilogue (second GCN): self term + LN + leaky + residual + out ----------------
// one wave per node, float2 per lane
__global__ __launch_bounds__(256) void k_epilogue(float* __restrict__ H,
                                                  const float* __restrict__ AGG,
                                                  const float* __restrict__ XL,
                                                  const float* __restrict__ root,
                                                  const float* __restrict__ idg,
                                                  const float* __restrict__ g, const float* __restrict__ b,
                                                  float* __restrict__ out, int layer_off) {
    int tid = threadIdx.x;
    int lane = tid & 63;
    int n = blockIdx.x * 4 + (tid >> 6);
    float2 a = ((const float2*)AGG)[(size_t)n * 64 + lane];
    float2 xv = ((const float2*)XL)[(size_t)n * 64 + lane];
    float2 rv = ((const float2*)root)[lane];
    float id = idg[n];
    float t0 = a.x + fmaxf(xv.x + rv.x, 0.0f) * id;
    float t1 = a.y + fmaxf(xv.y + rv.y, 0.0f) * id;

    float s = t0 + t1;
#pragma unroll
    for (int off = 32; off; off >>= 1) s += __shfl_xor(s, off, 64);
    float mu = s * (1.0f / 128.0f);
    float d0 = t0 - mu, d1 = t1 - mu;
    float q = d0 * d0 + d1 * d1;
#pragma unroll
    for (int off = 32; off; off >>= 1) q += __shfl_xor(q, off, 64);
    float rs = rsqrtf(q * (1.0f / 128.0f) + LNEPS);

    float2 gv = ((const float2*)g)[lane];
    float2 bv = ((const float2*)b)[lane];
    float y0 = leakyf(d0 * rs * gv.x + bv.x);
    float y1 = leakyf(d1 * rs * gv.y + bv.y);

    float2* h2 = (float2*)H + (size_t)n * 64 + lane;
    float2 hv = *h2;
    float2 o2; o2.x = y0 + hv.x; o2.y = y1 + hv.y;
    *h2 = o2;
    if (n < NI_C) ((float2*)out)[(size_t)n * 256 + (layer_off >> 1) + lane] = o2;
}

extern "C" void kernel_launch(void* const* d_in, const int* in_sizes, int n_in,
                              void* d_out, int out_size, void* d_ws, size_t ws_size,
                              hipStream_t stream) {
    const float* x         = (const float*)d_in[0];
    const float* enc_w1    = (const float*)d_in[1];
    const float* enc_b1    = (const float*)d_in[2];
    const float* enc_w2    = (const float*)d_in[3];
    const float* enc_b2    = (const float*)d_in[4];
    const float* conv_w    = (const float*)d_in[5];
    const float* conv_b    = (const float*)d_in[6];
    const float* conv_root = (const float*)d_in[7];
    const float* reconv_w    = (const float*)d_in[8];
    const float* reconv_b    = (const float*)d_in[9];
    const float* reconv_root = (const float*)d_in[10];
    const float* ln_g = (const float*)d_in[11];
    const float* ln_b = (const float*)d_in[12];
    const int* ei_nn  = (const int*)d_in[13];
    const int* ei_net = (const int*)d_in[14];
    float* out = (float*)d_out;

    char* ws = (char*)d_ws;
    size_t off = 0;
    const size_t big = (size_t)NN * EMB * sizeof(float);  // 102.4 MB
    float* H  = (float*)(ws + off); off += big;
    float* XL = (float*)(ws + off); off += big;
    float* HC = (float*)(ws + off); off += big;
    float* isq_nn  = (float*)(ws + off); off += (size_t)NN * 4;
    float* idg_nn  = (float*)(ws + off); off += (size_t)NN * 4;
    float* isq_net = (float*)(ws + off); off += (size_t)NN * 4;
    float* idg_net = (float*)(ws + off); off += (size_t)NN * 4;
    int* cnt_nn  = (int*)(ws + off); off += (size_t)NN * 4;
    int* cnt_net = (int*)(ws + off); off += (size_t)NN * 4;

    // degrees (reused by all layers)
    hipMemsetAsync(cnt_nn, 0, (size_t)NN * 4 * 2, stream);
    k_hist<<<(EE + 255) / 256, 256, 0, stream>>>(ei_nn, ei_net, cnt_nn, cnt_net);
    k_deg<<<(NN + 255) / 256, 256, 0, stream>>>(cnt_nn, cnt_net, isq_nn, idg_nn, isq_net, idg_net);

    // encoder -> H, out[:,0:128]
    k_encoder<<<NN / 64, 256, 0, stream>>>(x, enc_w1, enc_b1, enc_w2, enc_b2, H, out);

    for (int l = 0; l < 3; l++) {
        // GCN 1 (node_net edges)
        k_matmul<<<NN / 64, 256, 0, stream>>>(H, conv_w + (size_t)l * EMB * EMB, conv_b + l * EMB, XL);
        hipMemsetAsync(HC, 0, big, stream);
        k_scatter<<<EE / 4, 256, 0, stream>>>(XL, HC, ei_nn, isq_nn);
        k_self1<<<NN * EMB / 1024, 256, 0, stream>>>(HC, XL, conv_root + l * EMB, idg_nn);

        // GCN 2 (net_node edges) + LN + leaky + residual
        k_matmul<<<NN / 64, 256, 0, stream>>>(HC, reconv_w + (size_t)l * EMB * EMB, reconv_b + l * EMB, XL);
        hipMemsetAsync(HC, 0, big, stream);
        k_scatter<<<EE / 4, 256, 0, stream>>>(XL, HC, ei_net, isq_net);
        k_epilogue<<<NN / 4, 256, 0, stream>>>(H, HC, XL, reconv_root + l * EMB, idg_net,
                                               ln_g + l * EMB, ln_b + l * EMB, out, (l + 1) * EMB);
    }
}

// Round 2
// 2000.388 us; speedup vs baseline: 2.2225x; 2.2225x over previous
//
#include <hip/hip_runtime.h>
#include <hip/hip_bf16.h>

#define NN 200000
#define EE 600000
#define ND 32
#define EMB 128
#define NI_C 120000
#define NEGS 0.1f
#define LNEPS 1e-5f
#define CH 782   // (NN+255)/256 scan chunks

__device__ __forceinline__ float leakyf(float x) { return x >= 0.0f ? x : NEGS * x; }
__device__ __forceinline__ void fma4(float4& a, float s, const float4& w) {
    a.x = fmaf(s, w.x, a.x); a.y = fmaf(s, w.y, a.y);
    a.z = fmaf(s, w.z, a.z); a.w = fmaf(s, w.w, a.w);
}
__device__ __forceinline__ float bfu2f(unsigned int u) { return __uint_as_float(u << 16); }

// ---------------- histograms: row (for deg/isq) + col (for CSR) ----------------
__global__ __launch_bounds__(256) void k_hist(const int* __restrict__ ei_nn,
                                              const int* __restrict__ ei_net,
                                              int* __restrict__ cnt_nn, int* __restrict__ cnt_net,
                                              int* __restrict__ ccol_nn, int* __restrict__ ccol_net) {
    int e = blockIdx.x * 256 + threadIdx.x;
    if (e < EE) {
        atomicAdd(&cnt_nn[ei_nn[e]], 1);            // row histogram (deg)
        atomicAdd(&cnt_net[ei_net[e]], 1);
        atomicAdd(&ccol_nn[ei_nn[EE + e]], 1);      // col histogram (CSR)
        atomicAdd(&ccol_net[ei_net[EE + e]], 1);
    }
}

__global__ __launch_bounds__(256) void k_deg(const int* __restrict__ cnt_nn,
                                             const int* __restrict__ cnt_net,
                                             float* __restrict__ isq_nn, float* __restrict__ isq_net) {
    int n = blockIdx.x * 256 + threadIdx.x;
    if (n < NN) {
        isq_nn[n]  = rsqrtf((float)(cnt_nn[n] + 1));
        isq_net[n] = rsqrtf((float)(cnt_net[n] + 1));
    }
}

// ---------------- exclusive scan (3-kernel, 200k ints) ----------------
__global__ __launch_bounds__(256) void k_scan1(const int* __restrict__ cnt,
                                               int* __restrict__ ptr, int* __restrict__ bsum) {
    __shared__ int s[256];
    int t = threadIdx.x, i = blockIdx.x * 256 + t;
    int v = (i < NN) ? cnt[i] : 0;
    s[t] = v; __syncthreads();
    for (int off = 1; off < 256; off <<= 1) {
        int u = (t >= off) ? s[t - off] : 0;
        __syncthreads();
        s[t] += u; __syncthreads();
    }
    if (i < NN) ptr[i] = s[t] - v;
    if (t == 255) bsum[blockIdx.x] = s[255];
}

__global__ __launch_bounds__(1024) void k_scan2(int* __restrict__ bsum) {
    __shared__ int s[1024];
    int t = threadIdx.x;
    int v = (t < CH) ? bsum[t] : 0;
    s[t] = v; __syncthreads();
    for (int off = 1; off < 1024; off <<= 1) {
        int u = (t >= off) ? s[t - off] : 0;
        __syncthreads();
        s[t] += u; __syncthreads();
    }
    if (t < CH) bsum[t] = s[t] - v;   // exclusive block offsets
}

__global__ __launch_bounds__(256) void k_scan3(int* __restrict__ ptr, const int* __restrict__ bsum) {
    int i = blockIdx.x * 256 + threadIdx.x;
    if (i < NN) ptr[i] += bsum[blockIdx.x];
    if (i == 0) ptr[NN] = EE;
}

// ---------------- CSR fill (both directions) ----------------
__global__ __launch_bounds__(256) void k_fill(const int* __restrict__ ei_nn, const int* __restrict__ ei_net,
                                              const int* __restrict__ ptr_nn, const int* __restrict__ ptr_net,
                                              int* __restrict__ cur_nn, int* __restrict__ cur_net,
                                              int* __restrict__ adj_nn, int* __restrict__ adj_net) {
    int e = blockIdx.x * 256 + threadIdx.x;
    if (e < EE) {
        int c1 = ei_nn[EE + e];
        int p1 = ptr_nn[c1] + atomicAdd(&cur_nn[c1], 1);
        adj_nn[p1] = ei_nn[e];
        int c2 = ei_net[EE + e];
        int p2 = ptr_net[c2] + atomicAdd(&cur_net[c2], 1);
        adj_net[p2] = ei_net[e];
    }
}

// ---------------- encoder: h0 = leaky(leaky(x@W1+b1)@W2+b2) ----------------
__global__ __launch_bounds__(256) void k_encoder(const float* __restrict__ x,
                                                 const float* __restrict__ w1, const float* __restrict__ b1,
                                                 const float* __restrict__ w2, const float* __restrict__ b2,
                                                 float* __restrict__ H, float* __restrict__ out) {
    __shared__ float4 xs[512];
    __shared__ __align__(16) __hip_bfloat16 hs[64 * 256];
    int tid = threadIdx.x;
    int n0 = blockIdx.x * 64;

    const float4* xg = (const float4*)(x + (size_t)n0 * ND);
    for (int p = tid; p < 512; p += 256) xs[p] = xg[p];
    __syncthreads();

    {
        float w[32];
#pragma unroll
        for (int k = 0; k < 32; k++) w[k] = w1[k * 256 + tid];
        float bj = b1[tid];
        for (int n = 0; n < 64; n++) {
            float acc = bj;
#pragma unroll
            for (int k4 = 0; k4 < 8; k4++) {
                float4 xv = xs[n * 8 + k4];
                acc = fmaf(xv.x, w[4 * k4 + 0], acc);
                acc = fmaf(xv.y, w[4 * k4 + 1], acc);
                acc = fmaf(xv.z, w[4 * k4 + 2], acc);
                acc = fmaf(xv.w, w[4 * k4 + 3], acc);
            }
            hs[n * 256 + tid] = __float2bfloat16(leakyf(acc));
        }
    }
    __syncthreads();

    int tx = tid & 31, ty = tid >> 5;
    float4 bias = ((const float4*)b2)[tx];
    float4 acc[8];
#pragma unroll
    for (int i = 0; i < 8; i++) acc[i] = bias;

    const float4* w2g = (const float4*)w2;
    const unsigned short* hsu = (const unsigned short*)hs;
    for (int k4 = 0; k4 < 64; k4++) {
        float4 w0 = w2g[(4 * k4 + 0) * 32 + tx];
        float4 wv1 = w2g[(4 * k4 + 1) * 32 + tx];
        float4 wv2 = w2g[(4 * k4 + 2) * 32 + tx];
        float4 wv3 = w2g[(4 * k4 + 3) * 32 + tx];
#pragma unroll
        for (int i = 0; i < 8; i++) {
            int n = ty * 8 + i;
            uint2 hv = *(const uint2*)(hsu + n * 256 + 4 * k4);
            float a0 = bfu2f(hv.x & 0xffffu);
            float a1 = bfu2f(hv.x >> 16);
            float a2 = bfu2f(hv.y & 0xffffu);
            float a3 = bfu2f(hv.y >> 16);
            fma4(acc[i], a0, w0); fma4(acc[i], a1, wv1);
            fma4(acc[i], a2, wv2); fma4(acc[i], a3, wv3);
        }
    }
#pragma unroll
    for (int i = 0; i < 8; i++) {
        int n = n0 + ty * 8 + i;
        float4 v;
        v.x = leakyf(acc[i].x); v.y = leakyf(acc[i].y);
        v.z = leakyf(acc[i].z); v.w = leakyf(acc[i].w);
        ((float4*)H)[(size_t)n * 32 + tx] = v;
        if (n < NI_C) ((float4*)out)[(size_t)n * 128 + tx] = v;
    }
}

// ---------------- XL = A @ W + b ----------------
__global__ __launch_bounds__(256) void k_matmul(const float* __restrict__ A,
                                                const float* __restrict__ W,
                                                const float* __restrict__ bias,
                                                float* __restrict__ out) {
    __shared__ float4 As[2048];
    int tid = threadIdx.x;
    int n0 = blockIdx.x * 64;
    const float4* Ag = (const float4*)(A + (size_t)n0 * EMB);
    for (int p = tid; p < 2048; p += 256) As[p] = Ag[p];
    __syncthreads();

    int tx = tid & 31, ty = tid >> 5;
    const float4* Wg = (const float4*)W;
    float4 bias4 = ((const float4*)bias)[tx];
    float4 acc[8];
#pragma unroll
    for (int i = 0; i < 8; i++) acc[i] = bias4;

    for (int k4 = 0; k4 < 32; k4++) {
        float4 w0 = Wg[(4 * k4 + 0) * 32 + tx];
        float4 w1 = Wg[(4 * k4 + 1) * 32 + tx];
        float4 w2 = Wg[(4 * k4 + 2) * 32 + tx];
        float4 w3 = Wg[(4 * k4 + 3) * 32 + tx];
#pragma unroll
        for (int i = 0; i < 8; i++) {
            float4 a = As[(ty * 8 + i) * 32 + k4];
            fma4(acc[i], a.x, w0); fma4(acc[i], a.y, w1);
            fma4(acc[i], a.z, w2); fma4(acc[i], a.w, w3);
        }
    }
    float4* og = (float4*)out;
#pragma unroll
    for (int i = 0; i < 8; i++) og[(size_t)(n0 + ty * 8 + i) * 32 + tx] = acc[i];
}

// ---------------- fused gather 1: AGG = isq[n]*sum(isq[r]*relu(XL[r])) + relu(XL[n]+root)*isq[n]^2
__global__ __launch_bounds__(256) void k_gather1(const float* __restrict__ XL,
                                                 float* __restrict__ AGG,
                                                 const int* __restrict__ adj, const int* __restrict__ ptr,
                                                 const float* __restrict__ isq,
                                                 const float* __restrict__ root) {
    int tid = threadIdx.x;
    int lane = tid & 63;
    int n = blockIdx.x * 4 + (tid >> 6);
    int s = ptr[n], e = ptr[n + 1];
    float a0 = 0.0f, a1 = 0.0f;
    for (int i = s; i < e; i++) {
        int r = adj[i];
        float w = isq[r];
        float2 v = ((const float2*)XL)[(size_t)r * 64 + lane];
        a0 = fmaf(w, fmaxf(v.x, 0.0f), a0);
        a1 = fmaf(w, fmaxf(v.y, 0.0f), a1);
    }
    float iq = isq[n];
    float id = iq * iq;
    float2 xv = ((const float2*)XL)[(size_t)n * 64 + lane];
    float2 rv = ((const float2*)root)[lane];
    float2 o;
    o.x = iq * a0 + fmaxf(xv.x + rv.x, 0.0f) * id;
    o.y = iq * a1 + fmaxf(xv.y + rv.y, 0.0f) * id;
    ((float2*)AGG)[(size_t)n * 64 + lane] = o;
}

// ---------------- fused gather 2: gather + self + LN + leaky + residual + out slice
__global__ __launch_bounds__(256) void k_gather2(const float* __restrict__ XL,
                                                 float* __restrict__ H,
                                                 const int* __restrict__ adj, const int* __restrict__ ptr,
                                                 const float* __restrict__ isq,
                                                 const float* __restrict__ root,
                                                 const float* __restrict__ g, const float* __restrict__ b,
                                                 float* __restrict__ out, int layer_off) {
    int tid = threadIdx.x;
    int lane = tid & 63;
    int n = blockIdx.x * 4 + (tid >> 6);
    int s = ptr[n], e = ptr[n + 1];
    float a0 = 0.0f, a1 = 0.0f;
    for (int i = s; i < e; i++) {
        int r = adj[i];
        float w = isq[r];
        float2 v = ((const float2*)XL)[(size_t)r * 64 + lane];
        a0 = fmaf(w, fmaxf(v.x, 0.0f), a0);
        a1 = fmaf(w, fmaxf(v.y, 0.0f), a1);
    }
    float iq = isq[n];
    float id = iq * iq;
    float2 xv = ((const float2*)XL)[(size_t)n * 64 + lane];
    float2 rv = ((const float2*)root)[lane];
    float t0 = iq * a0 + fmaxf(xv.x + rv.x, 0.0f) * id;
    float t1 = iq * a1 + fmaxf(xv.y + rv.y, 0.0f) * id;

    float sm = t0 + t1;
#pragma unroll
    for (int off = 32; off; off >>= 1) sm += __shfl_xor(sm, off, 64);
    float mu = sm * (1.0f / 128.0f);
    float d0 = t0 - mu, d1 = t1 - mu;
    float q = d0 * d0 + d1 * d1;
#pragma unroll
    for (int off = 32; off; off >>= 1) q += __shfl_xor(q, off, 64);
    float rs = rsqrtf(q * (1.0f / 128.0f) + LNEPS);

    float2 gv = ((const float2*)g)[lane];
    float2 bv = ((const float2*)b)[lane];
    float y0 = leakyf(d0 * rs * gv.x + bv.x);
    float y1 = leakyf(d1 * rs * gv.y + bv.y);

    float2* h2 = (float2*)H + (size_t)n * 64 + lane;
    float2 hv = *h2;
    float2 o2; o2.x = y0 + hv.x; o2.y = y1 + hv.y;
    *h2 = o2;
    if (n < NI_C) ((float2*)out)[(size_t)n * 256 + (layer_off >> 1) + lane] = o2;
}

extern "C" void kernel_launch(void* const* d_in, const int* in_sizes, int n_in,
                              void* d_out, int out_size, void* d_ws, size_t ws_size,
                              hipStream_t stream) {
    const float* x         = (const float*)d_in[0];
    const float* enc_w1    = (const float*)d_in[1];
    const float* enc_b1    = (const float*)d_in[2];
    const float* enc_w2    = (const float*)d_in[3];
    const float* enc_b2    = (const float*)d_in[4];
    const float* conv_w    = (const float*)d_in[5];
    const float* conv_b    = (const float*)d_in[6];
    const float* conv_root = (const float*)d_in[7];
    const float* reconv_w    = (const float*)d_in[8];
    const float* reconv_b    = (const float*)d_in[9];
    const float* reconv_root = (const float*)d_in[10];
    const float* ln_g = (const float*)d_in[11];
    const float* ln_b = (const float*)d_in[12];
    const int* ei_nn  = (const int*)d_in[13];
    const int* ei_net = (const int*)d_in[14];
    float* out = (float*)d_out;

    char* ws = (char*)d_ws;
    size_t off = 0;
    const size_t big = (size_t)NN * EMB * sizeof(float);  // 102.4 MB
    float* H  = (float*)(ws + off); off += big;
    float* XL = (float*)(ws + off); off += big;
    float* HC = (float*)(ws + off); off += big;
    float* isq_nn  = (float*)(ws + off); off += (size_t)NN * 4;
    float* isq_net = (float*)(ws + off); off += (size_t)NN * 4;
    // histogram block (contiguous for single memset): cnt_nn, cnt_net, ccol_nn, ccol_net
    int* cnt_nn  = (int*)(ws + off); off += (size_t)NN * 4;   // reused as cur_nn after k_deg
    int* cnt_net = (int*)(ws + off); off += (size_t)NN * 4;   // reused as cur_net
    int* ccol_nn  = (int*)(ws + off); off += (size_t)NN * 4;
    int* ccol_net = (int*)(ws + off); off += (size_t)NN * 4;
    int* ptr_nn  = (int*)(ws + off); off += (size_t)(NN + 1) * 4;
    int* ptr_net = (int*)(ws + off); off += (size_t)(NN + 1) * 4;
    int* adj_nn  = (int*)(ws + off); off += (size_t)EE * 4;
    int* adj_net = (int*)(ws + off); off += (size_t)EE * 4;
    int* bsum_nn  = (int*)(ws + off); off += (size_t)1024 * 4;
    int* bsum_net = (int*)(ws + off); off += (size_t)1024 * 4;

    // ---- CSR + degree build (once per launch, reused by all 3 layers) ----
    hipMemsetAsync(cnt_nn, 0, (size_t)NN * 4 * 4, stream);  // all 4 histograms
    k_hist<<<(EE + 255) / 256, 256, 0, stream>>>(ei_nn, ei_net, cnt_nn, cnt_net, ccol_nn, ccol_net);
    k_deg<<<(NN + 255) / 256, 256, 0, stream>>>(cnt_nn, cnt_net, isq_nn, isq_net);
    k_scan1<<<CH, 256, 0, stream>>>(ccol_nn, ptr_nn, bsum_nn);
    k_scan1<<<CH, 256, 0, stream>>>(ccol_net, ptr_net, bsum_net);
    k_scan2<<<1, 1024, 0, stream>>>(bsum_nn);
    k_scan2<<<1, 1024, 0, stream>>>(bsum_net);
    k_scan3<<<CH, 256, 0, stream>>>(ptr_nn, bsum_nn);
    k_scan3<<<CH, 256, 0, stream>>>(ptr_net, bsum_net);
    hipMemsetAsync(cnt_nn, 0, (size_t)NN * 4 * 2, stream);  // zero fill cursors (reuse cnt)
    k_fill<<<(EE + 255) / 256, 256, 0, stream>>>(ei_nn, ei_net, ptr_nn, ptr_net,
                                                 cnt_nn, cnt_net, adj_nn, adj_net);

    // ---- encoder -> H, out[:,0:128] ----
    k_encoder<<<NN / 64, 256, 0, stream>>>(x, enc_w1, enc_b1, enc_w2, enc_b2, H, out);

    for (int l = 0; l < 3; l++) {
        // GCN 1 (node_net edges)
        k_matmul<<<NN / 64, 256, 0, stream>>>(H, conv_w + (size_t)l * EMB * EMB, conv_b + l * EMB, XL);
        k_gather1<<<NN / 4, 256, 0, stream>>>(XL, HC, adj_nn, ptr_nn, isq_nn, conv_root + l * EMB);

        // GCN 2 (net_node edges) + LN + leaky + residual
        k_matmul<<<NN / 64, 256, 0, stream>>>(HC, reconv_w + (size_t)l * EMB * EMB, reconv_b + l * EMB, XL);
        k_gather2<<<NN / 4, 256, 0, stream>>>(XL, H, adj_net, ptr_net, isq_net, reconv_root + l * EMB,
                                              ln_g + l * EMB, ln_b + l * EMB, out, (l + 1) * EMB);
    }
}